// Round 1
// baseline (478.731 us; speedup 1.0000x reference)
//
#include <hip/hip_runtime.h>
#include <math.h>

// Problem constants (from reference): B=64, L=1024, C=128, K=6, P=6, Dp=8, D=4, Dd=12, ITERS=2
#define EPSQ 1e-9f

constexpr int C    = 128;
constexpr int K    = 6;
constexpr int PD   = 48;   // P*Dp
constexpr int DD   = 48;   // D*Dd
constexpr int NPOS = 8;    // positions per block (2 per wave)
constexpr int WROW = 52;   // padded LDS row for W_k (breaks bank-group clustering)

__device__ __forceinline__ float g8sum(float x) {
    x += __shfl_xor(x, 1);
    x += __shfl_xor(x, 2);
    x += __shfl_xor(x, 4);
    return x;
}
__device__ __forceinline__ float g16sum(float x) {
    x += __shfl_xor(x, 1);
    x += __shfl_xor(x, 2);
    x += __shfl_xor(x, 4);
    x += __shfl_xor(x, 8);
    return x;
}

// Dynamic routing (ITERS=2) + output write, all in registers/shuffles.
// Lane layout: lane = d*16 + q, q<12 active.
__device__ __forceinline__ void route_and_write(const float* uh, int d, int q, bool act,
                                                float* __restrict__ out, long pos)
{
    // iter 1: c = softmax(0) = 0.25 uniform
    float s = 0.f;
    #pragma unroll
    for (int k = 0; k < K; ++k) s += uh[k];
    s *= 0.25f;
    float s2 = g16sum(s * s);                       // sum over q (Dd)
    float v = s * (s2 / (1.0f + s2) / (sqrtf(s2) + EPSQ));

    // iter 2: b[k,d] = sum_q uh[k,d,q]*v[d,q]; c = softmax_d(b); s = sum_k c*uh
    float ss = 0.f;
    #pragma unroll
    for (int k = 0; k < K; ++k) {
        float b = g16sum(uh[k] * v);                // all lanes in d-group get b[k,d]
        float m = fmaxf(b, __shfl_xor(b, 16));      // max over d (4 groups)
        m = fmaxf(m, __shfl_xor(m, 32));
        float e = expf(b - m);
        float es = e + __shfl_xor(e, 16);
        es += __shfl_xor(es, 32);
        ss = fmaf(e / es, uh[k], ss);
    }
    float ss2 = g16sum(ss * ss);
    float vv = ss * (ss2 / (1.0f + ss2) / (sqrtf(ss2) + EPSQ));
    if (act) out[pos * DD + d * 12 + q] = vv;
}

__global__ __launch_bounds__(256, 3) void capsule_kernel(
    const float* __restrict__ X,    // [B*L][C][K] = [65536][128][6]
    const float* __restrict__ Wp,   // [48][128]
    const float* __restrict__ bp,   // [48]
    const float* __restrict__ W,    // [6][48(dq)][48(p)]
    float* __restrict__ out)        // [65536][48]
{
    __shared__ __align__(16) float sXk[NPOS * C * K];   // 6144 floats, raw X blocks
    __shared__ __align__(16) float sXp[NPOS * K * PD];  // 2304 floats, squashed primaries
    __shared__ __align__(16) float sWk[DD * WROW];      // 2496 floats, one k-slice of W (padded rows)

    const int t = threadIdx.x;
    const int wave = t >> 6;
    const int lane = t & 63;
    const long pos_base = (long)blockIdx.x * NPOS;

    // ---- stage X for 8 consecutive positions: 6144 floats = 1536 float4, fully coalesced
    {
        const float4* __restrict__ src = (const float4*)(X + pos_base * (C * K));
        float4* dst = (float4*)sXk;
        #pragma unroll
        for (int i = 0; i < 6; ++i) dst[t + 256 * i] = src[t + 256 * i];
    }
    __syncthreads();

    // ---- projection + squash; lane = p in [0,48). Wave w handles positions w and w+4.
    if (lane < PD) {
        const int p = lane;
        float acc0[K], acc1[K];
        const float bias = bp[p];
        #pragma unroll
        for (int k = 0; k < K; ++k) { acc0[k] = bias; acc1[k] = bias; }

        const float4* __restrict__ wrow = (const float4*)(Wp + p * C);  // lane-private row, L1-resident
        const float4* x0 = (const float4*)(sXk + wave * (C * K));
        const float4* x1 = (const float4*)(sXk + (wave + 4) * (C * K));

        #pragma unroll 2
        for (int cq = 0; cq < C / 4; ++cq) {
            const float4 wq = wrow[cq];
            float4 m0[6], m1[6];                    // 24 floats = X[c..c+3][k=0..5] per position
            #pragma unroll
            for (int i = 0; i < 6; ++i) { m0[i] = x0[cq * 6 + i]; m1[i] = x1[cq * 6 + i]; }
            const float* a0 = (const float*)m0;
            const float* a1 = (const float*)m1;
            const float* w4 = (const float*)&wq;
            #pragma unroll
            for (int j = 0; j < 4; ++j) {
                #pragma unroll
                for (int k = 0; k < K; ++k) {
                    acc0[k] = fmaf(a0[j * 6 + k], w4[j], acc0[k]);
                    acc1[k] = fmaf(a1[j * 6 + k], w4[j], acc1[k]);
                }
            }
        }
        // squash over Dp=8 (8-lane capsule groups), write to LDS for the u_hat phase
        #pragma unroll
        for (int k = 0; k < K; ++k) {
            float s2a = g8sum(acc0[k] * acc0[k]);
            float s2b = g8sum(acc1[k] * acc1[k]);
            float ra = s2a / (1.0f + s2a) / (sqrtf(s2a) + EPSQ);
            float rb = s2b / (1.0f + s2b) / (sqrtf(s2b) + EPSQ);
            sXp[wave * (K * PD) + k * PD + p]       = acc0[k] * ra;
            sXp[(wave + 4) * (K * PD) + k * PD + p] = acc1[k] * rb;
        }
    }

    // ---- u_hat: lane = d*16 + q (q<12 active); uh[k] = sum_p W[k][dq][p] * Xp[k][p]
    const int d = lane >> 4;
    const int q = lane & 15;
    const bool act = (q < 12);
    const int dq = d * 12 + (act ? q : 11);   // clamp inactive lanes to a valid row

    float uh0[K], uh1[K];
    #pragma unroll
    for (int k = 0; k < K; ++k) {
        __syncthreads();
        // stage W[k] (2304 floats) into padded LDS rows; coalesced global float4 reads
        {
            const float4* __restrict__ wsrc = (const float4*)(W + (long)k * (DD * PD));
            for (int i = t; i < DD * 12; i += 256) {
                int row = i / 12, j = i % 12;
                *(float4*)(sWk + row * WROW + j * 4) = wsrc[i];
            }
        }
        __syncthreads();

        const float4* wr = (const float4*)(sWk + dq * WROW);                 // lane-private row
        const float4* a0 = (const float4*)(sXp + wave * (K * PD) + k * PD);  // wave-uniform (broadcast)
        const float4* a1 = (const float4*)(sXp + (wave + 4) * (K * PD) + k * PD);
        float u0 = 0.f, u1 = 0.f;
        #pragma unroll
        for (int j = 0; j < 12; ++j) {
            float4 wv = wr[j];
            float4 p0 = a0[j];
            float4 p1 = a1[j];
            u0 = fmaf(wv.x, p0.x, u0); u0 = fmaf(wv.y, p0.y, u0);
            u0 = fmaf(wv.z, p0.z, u0); u0 = fmaf(wv.w, p0.w, u0);
            u1 = fmaf(wv.x, p1.x, u1); u1 = fmaf(wv.y, p1.y, u1);
            u1 = fmaf(wv.z, p1.z, u1); u1 = fmaf(wv.w, p1.w, u1);
        }
        uh0[k] = act ? u0 : 0.f;
        uh1[k] = act ? u1 : 0.f;
    }

    // ---- dynamic routing (2 iters) per position, registers + shuffles only
    route_and_write(uh0, d, q, act, out, pos_base + wave);
    route_and_write(uh1, d, q, act, out, pos_base + wave + 4);
}

extern "C" void kernel_launch(void* const* d_in, const int* in_sizes, int n_in,
                              void* d_out, int out_size, void* d_ws, size_t ws_size,
                              hipStream_t stream) {
    const float* X  = (const float*)d_in[0];   // [64,1024,128,6]
    const float* Wp = (const float*)d_in[1];   // [48,128]
    const float* bp = (const float*)d_in[2];   // [48]
    const float* W  = (const float*)d_in[3];   // [6,4,12,48]
    float* out = (float*)d_out;                // [65536,48]

    const int n_pos = 64 * 1024;               // B*L
    dim3 grid(n_pos / NPOS), block(256);
    hipLaunchKernelGGL(capsule_kernel, grid, block, 0, stream, X, Wp, bp, W, out);
}